// Round 15
// baseline (154.064 us; speedup 1.0000x reference)
//
#include <hip/hip_runtime.h>
#include <hip/hip_bf16.h>

#define BN 8192
#define DIM 512
#define NB  64            // BN / 128 block-rows
#define NBLK 1056         // sum over bi of ceil((64-bi)/2)  (2 tiles/block)
#define EPSF 1e-8f

using v8i   = __attribute__((ext_vector_type(8))) int;
using v4i   = __attribute__((ext_vector_type(4))) int;
using f32x4 = __attribute__((ext_vector_type(4))) float;

// Async global->LDS, 16 B per lane, dest = uniform base + lane*16.
__device__ __forceinline__ void async_copy16(const void* g, void* l) {
    __builtin_amdgcn_global_load_lds(
        (const __attribute__((address_space(1))) void*)g,
        (__attribute__((address_space(3))) void*)l,
        16, 0, 0);
}

// One wave per row: L2-normalize, x4 pre-scale, fp8 e4m3; out[0] zeroed by
// block 0 (replaces a memset dispatch).
__global__ __launch_bounds__(256) void normalize_kernel(
        const float* __restrict__ emb, unsigned char* __restrict__ E,
        float* __restrict__ out) {
    if (blockIdx.x == 0 && threadIdx.x == 0) out[0] = 0.f;
    int lane = threadIdx.x & 63;
    int row  = blockIdx.x * 4 + (threadIdx.x >> 6);
    const float4* src = (const float4*)(emb + (size_t)row * DIM);
    float4 a = src[lane];
    float4 b = src[lane + 64];
    float ss = a.x*a.x + a.y*a.y + a.z*a.z + a.w*a.w
             + b.x*b.x + b.y*b.y + b.z*b.z + b.w*b.w;
    #pragma unroll
    for (int m = 1; m < 64; m <<= 1) ss += __shfl_xor(ss, m, 64);
    float s4 = 4.0f / fmaxf(sqrtf(ss), 1e-12f);
    int pa = __builtin_amdgcn_cvt_pk_fp8_f32(a.x*s4, a.y*s4, 0, false);
    pa     = __builtin_amdgcn_cvt_pk_fp8_f32(a.z*s4, a.w*s4, pa, true);
    int pb = __builtin_amdgcn_cvt_pk_fp8_f32(b.x*s4, b.y*s4, 0, false);
    pb     = __builtin_amdgcn_cvt_pk_fp8_f32(b.z*s4, b.w*s4, pb, true);
    unsigned char* rowp = E + (size_t)row * DIM;
    ((unsigned*)rowp)[lane]         = (unsigned)pa;
    ((unsigned*)(rowp + 256))[lane] = (unsigned)pb;
}

// TWO upper-triangle 128x128 tiles per block: (bi, bj0) and (bi, bj0+1).
// Both share the A-slab (same bi): A staged ONCE (two BK=256 chunks, XOR
// swizzle), and both tiles' MFMAs consume the SAME af fragments -> A ds_reads,
// staging traffic and barrier-drain rounds per tile all halve; MFMA:staging
// ratio doubles. B direct global->VGPR (L2-resident E). fp8 MX 16x16x128.
// acc[2][4][4] = 128 VGPRs; est total ~180 (2 waves/SIMD, no spill).
// Singleton rows (odd tile count): tile1 disabled -- B rows clamped, writes
// skipped. Epilogue per tile, sequential, reusing the LDS reduction buffers.
__global__ __launch_bounds__(256) void gemm_epi_kernel(
        const unsigned char* __restrict__ E, const int* __restrict__ labels,
        float* __restrict__ P, float* __restrict__ N) {
    __shared__ __attribute__((aligned(16))) unsigned char smem[45056];
    __shared__ int labI[128];
    __shared__ int labJ[256];

    // decode t -> (bi, pair index): row bi has ceil((64-bi)/2) blocks.
    int rem = blockIdx.x;
    int bi  = 0;
    for (;;) {
        int cnt = (65 - bi) >> 1;
        if (rem < cnt) break;
        rem -= cnt;
        ++bi;
    }
    const int  bj0  = bi + 2 * rem;
    const bool has2 = (bj0 + 1) <= 63;
    const bool diag = (bi == bj0);
    const int  i0   = bi * 128;
    const int  j0   = bj0 * 128;

    const int tid  = threadIdx.x;
    const int wave = tid >> 6;
    const int lane = tid & 63;
    const int quad = lane >> 4;
    const int lrow = lane & 15;
    const int i_w  = (wave >> 1) * 64;
    const int j_w  = (wave & 1) * 64;

    if (tid < 128) labI[tid] = labels[i0 + tid];
    labJ[tid] = labels[min(j0 + tid, BN - 1)];

    unsigned char* As = smem;
    float2* rowBuf = (float2*)smem;               // [2][128][17]
    float2* colBuf = (float2*)(smem + 34816);     // [2][128][5]
    const int vR = wave & 1;
    const int vC = wave >> 1;

    f32x4 acc[2][4][4];
    #pragma unroll
    for (int s = 0; s < 2; ++s)
        #pragma unroll
        for (int a = 0; a < 4; ++a)
            #pragma unroll
            for (int b = 0; b < 4; ++b)
                acc[s][a][b] = (f32x4){0.f, 0.f, 0.f, 0.f};

    // B base pointers for both tiles (tile1 rows clamped when absent).
    const v4i* bptr0[4];
    const v4i* bptr1[4];
    #pragma unroll
    for (int tj = 0; tj < 4; ++tj) {
        int jr0 = j0 + j_w + tj * 16 + lrow;
        int jr1 = min(jr0 + 128, BN - 1);
        bptr0[tj] = (const v4i*)(E + (size_t)jr0 * DIM + quad * 32);
        bptr1[tj] = (const v4i*)(E + (size_t)jr1 * DIM + quad * 32);
    }

    // Two BK=256 A-chunks. Stage: wave rows [w*32,w*32+32), 8 instrs x 4 rows;
    // lane l: row base+(l>>4), LDS chunk p=l&15 holds global chunk p^(row&7).
    #pragma unroll
    for (int c = 0; c < 2; ++c) {
        if (c) __syncthreads();           // chunk0 ds_reads done
        #pragma unroll
        for (int h = 0; h < 8; ++h) {
            int base = wave * 32 + h * 4;
            int rowg = base + (lane >> 4);
            int g    = (lane & 15) ^ (rowg & 7);
            async_copy16(E + (size_t)(i0 + rowg) * DIM + c * 256 + g * 16,
                         As + (size_t)base * 256);
        }
        __syncthreads();                  // vmcnt drain: chunk ready

        #pragma unroll
        for (int k2 = 0; k2 < 2; ++k2) {
            const int k = c * 2 + k2;
            v8i af[4];
            #pragma unroll
            for (int ti = 0; ti < 4; ++ti) {
                int r  = i_w + ti * 16 + lrow;
                const v4i* rp = (const v4i*)(As + (size_t)r * 256);
                int sw = r & 7;
                ((v4i*)&af[ti])[0] = rp[(k2 * 8 + quad * 2) ^ sw];
                ((v4i*)&af[ti])[1] = rp[(k2 * 8 + quad * 2 + 1) ^ sw];
            }
            v8i bf0[4], bf1[4];
            #pragma unroll
            for (int tj = 0; tj < 4; ++tj) {
                ((v4i*)&bf0[tj])[0] = bptr0[tj][k * 8];
                ((v4i*)&bf0[tj])[1] = bptr0[tj][k * 8 + 1];
                ((v4i*)&bf1[tj])[0] = bptr1[tj][k * 8];
                ((v4i*)&bf1[tj])[1] = bptr1[tj][k * 8 + 1];
            }
            #pragma unroll
            for (int ti = 0; ti < 4; ++ti)
                #pragma unroll
                for (int tj = 0; tj < 4; ++tj) {
                    acc[0][ti][tj] =
                        __builtin_amdgcn_mfma_scale_f32_16x16x128_f8f6f4(
                            af[ti], bf0[tj], acc[0][ti][tj],
                            0, 0, 0, 0x7F7F7F7F, 0, 0x7F7F7F7F);
                    acc[1][ti][tj] =
                        __builtin_amdgcn_mfma_scale_f32_16x16x128_f8f6f4(
                            af[ti], bf1[tj], acc[1][ti][tj],
                            0, 0, 0, 0x7F7F7F7F, 0, 0x7F7F7F7F);
                }
        }
    }
    __syncthreads();      // As dead -> reduction buffers writable

    // Per-tile epilogue (sequential, LDS buffers reused with barriers).
    // C/D: col = lane&15, row = quad*4 + reg. acc = 16*S.
    for (int tt = 0; tt < 2; ++tt) {
        if (tt == 1 && !has2) break;
        const int  jbase = tt * 128;
        const int  bjt   = bj0 + tt;
        const int  j0t   = j0 + jbase;
        const bool dg    = diag && (tt == 0);

        float psC[4] = {0.f, 0.f, 0.f, 0.f};
        float nsC[4] = {0.f, 0.f, 0.f, 0.f};
        #pragma unroll
        for (int ti = 0; ti < 4; ++ti) {
            #pragma unroll
            for (int reg = 0; reg < 4; ++reg) {
                int irow = i_w + ti * 16 + quad * 4 + reg;
                int li   = labI[irow];
                int gi   = i0 + irow;
                float ps = 0.f, ns = 0.f;
                #pragma unroll
                for (int tj = 0; tj < 4; ++tj) {
                    int jcol = j_w + tj * 16 + lrow;
                    int lj   = labJ[jbase + jcol];
                    int gj   = j0t + jcol;
                    float w  = __expf(fmaf(acc[tt][ti][tj][reg], 0.0625f, -1.0f));
                    bool same = (li == lj);
                    float wp = (same && (gi != gj)) ? w : 0.f;
                    float wn = same ? 0.f : w;
                    ps += wp;  ns += wn;
                    psC[tj] += wp;  nsC[tj] += wn;
                }
                rowBuf[(size_t)(vR * 128 + irow) * 17 + lrow] = (float2){ps, ns};
            }
        }
        #pragma unroll
        for (int tj = 0; tj < 4; ++tj) {
            int jcol = j_w + tj * 16 + lrow;
            colBuf[(size_t)(vC * 128 + jcol) * 5 + quad] =
                (float2){psC[tj], nsC[tj]};
        }
        __syncthreads();

        if (tid < 128) {
            const float2* a = rowBuf + (size_t)tid * 17;
            const float2* b = rowBuf + (size_t)(128 + tid) * 17;
            float sp = 0.f, sn = 0.f;
            #pragma unroll
            for (int u2 = 0; u2 < 16; ++u2) {
                sp += a[u2].x + b[u2].x;
                sn += a[u2].y + b[u2].y;
            }
            P[(size_t)bjt * BN + i0 + tid] = sp;
            N[(size_t)bjt * BN + i0 + tid] = sn;
        } else if (!dg) {
            int c2 = tid - 128;
            const float2* a = colBuf + (size_t)c2 * 5;
            const float2* b = colBuf + (size_t)(128 + c2) * 5;
            float sp = 0.f, sn = 0.f;
            #pragma unroll
            for (int u2 = 0; u2 < 4; ++u2) {
                sp += a[u2].x + b[u2].x;
                sn += a[u2].y + b[u2].y;
            }
            P[(size_t)bi * BN + j0t + c2] = sp;
            N[(size_t)bi * BN + j0t + c2] = sn;
        }
        __syncthreads();   // buffers consumed before next tile reuses them
    }
}

// Fused tail: 32 blocks x 256. Per-block LDS histogram, per-row partial
// reduce + loss, one atomicAdd of the pre-scaled block sum into out[0].
__global__ __launch_bounds__(256) void reduce_finalize_kernel(
        const int* __restrict__ labels, const float* __restrict__ P,
        const float* __restrict__ N, float* __restrict__ out) {
    __shared__ int cnt[128];
    __shared__ float wsum[4];
    int tid = threadIdx.x;
    if (tid < 128) cnt[tid] = 0;
    __syncthreads();
    for (int i = tid; i < BN; i += 256) atomicAdd(&cnt[labels[i]], 1);
    __syncthreads();

    int i = blockIdx.x * 256 + tid;
    float p = 0.f, n = 0.f;
    #pragma unroll 8
    for (int c = 0; c < NB; ++c) {
        p += P[(size_t)c * BN + i];
        n += N[(size_t)c * BN + i];
    }
    int   cl = cnt[labels[i]];
    float pm = p / fmaxf((float)(cl - 1), 1.0f);
    float nm = n / fmaxf((float)(BN - cl), 1.0f);
    float v  = ((cl - 1 > 0) && (BN - cl > 0))
                   ? -logf(pm / (pm + nm + EPSF)) : 0.0f;
    v *= (1.0f / (float)BN);
    #pragma unroll
    for (int m = 1; m < 64; m <<= 1) v += __shfl_xor(v, m, 64);
    if ((tid & 63) == 0) wsum[tid >> 6] = v;
    __syncthreads();
    if (tid == 0)
        atomicAdd(out, wsum[0] + wsum[1] + wsum[2] + wsum[3]);
}

extern "C" void kernel_launch(void* const* d_in, const int* in_sizes, int n_in,
                              void* d_out, int out_size, void* d_ws, size_t ws_size,
                              hipStream_t stream) {
    const float* emb   = (const float*)d_in[0];
    const int* labels  = (const int*)d_in[1];
    float* out         = (float*)d_out;

    // ws layout: E (8 MB reserved; fp8 uses 4) | P (2 MB) | N (2 MB)
    unsigned char* E   = (unsigned char*)d_ws;
    float* P           = (float*)((char*)d_ws + (size_t)BN * DIM * 2);
    float* N           = P + (size_t)NB * BN;

    normalize_kernel<<<BN / 4, 256, 0, stream>>>(emb, E, out);
    gemm_epi_kernel<<<NBLK, 256, 0, stream>>>(E, labels, P, N);
    reduce_finalize_kernel<<<32, 256, 0, stream>>>(labels, P, N, out);
}

// Round 16
// 153.329 us; speedup vs baseline: 1.0048x; 1.0048x over previous
//
#include <hip/hip_runtime.h>
#include <hip/hip_bf16.h>

#define BN 8192
#define DIM 512
#define NB  64            // BN / 128 block-rows
#define NTILES 2080       // NB*(NB+1)/2 upper-triangle tiles
#define EPSF 1e-8f

using v8i   = __attribute__((ext_vector_type(8))) int;
using v4i   = __attribute__((ext_vector_type(4))) int;
using f32x4 = __attribute__((ext_vector_type(4))) float;

// Async global->LDS, 16 B per lane, dest = uniform base + lane*16.
__device__ __forceinline__ void async_copy16(const void* g, void* l) {
    __builtin_amdgcn_global_load_lds(
        (const __attribute__((address_space(1))) void*)g,
        (__attribute__((address_space(3))) void*)l,
        16, 0, 0);
}

// One wave per row: L2-normalize, x4 pre-scale, fp8 e4m3; out[0] zeroed by
// block 0 (replaces a memset dispatch).
__global__ __launch_bounds__(256) void normalize_kernel(
        const float* __restrict__ emb, unsigned char* __restrict__ E,
        float* __restrict__ out) {
    if (blockIdx.x == 0 && threadIdx.x == 0) out[0] = 0.f;
    int lane = threadIdx.x & 63;
    int row  = blockIdx.x * 4 + (threadIdx.x >> 6);
    const float4* src = (const float4*)(emb + (size_t)row * DIM);
    float4 a = src[lane];
    float4 b = src[lane + 64];
    float ss = a.x*a.x + a.y*a.y + a.z*a.z + a.w*a.w
             + b.x*b.x + b.y*b.y + b.z*b.z + b.w*b.w;
    #pragma unroll
    for (int m = 1; m < 64; m <<= 1) ss += __shfl_xor(ss, m, 64);
    float s4 = 4.0f / fmaxf(sqrtf(ss), 1e-12f);
    int pa = __builtin_amdgcn_cvt_pk_fp8_f32(a.x*s4, a.y*s4, 0, false);
    pa     = __builtin_amdgcn_cvt_pk_fp8_f32(a.z*s4, a.w*s4, pa, true);
    int pb = __builtin_amdgcn_cvt_pk_fp8_f32(b.x*s4, b.y*s4, 0, false);
    pb     = __builtin_amdgcn_cvt_pk_fp8_f32(b.z*s4, b.w*s4, pb, true);
    unsigned char* rowp = E + (size_t)row * DIM;
    ((unsigned*)rowp)[lane]         = (unsigned)pa;
    ((unsigned*)(rowp + 256))[lane] = (unsigned)pb;
}

// Upper-triangle 128x128 tiles, 1D grid (2080), triangular decode.
// R11 core: A-slab in LDS as two BK=256 chunks (XOR swizzle, single-buffer);
// B direct global->VGPR (L2-resident E) with register double-buffer; fp8 MX
// MFMA 16x16x128. R16 delta: COMPACT epilogue (R12's proven shfl_xor(8)
// pre-reduce) so rowBuf [2][128][9]f2 (18.4 KB) + colBuf [2][128][5]f2
// (10 KB) = 28.7 KB fit INSIDE the 32 KB As overlay -> total LDS ~33.8 KB ->
// 4 blocks/CU by LDS (VGPR 128 -> 4 waves/SIMD supports 4x4 waves), vs ~2-3
// at R11's 46 KB. Pure occupancy push; K-loop untouched.
__global__ __launch_bounds__(256) void gemm_epi_kernel(
        const unsigned char* __restrict__ E, const int* __restrict__ labels,
        float* __restrict__ P, float* __restrict__ N) {
    __shared__ __attribute__((aligned(16))) unsigned char smem[32768];
    __shared__ int labI[128];
    __shared__ int labJ[128];

    int t  = blockIdx.x;
    int bi = (int)(64.5f - sqrtf(64.5f * 64.5f - 2.0f * (float)t));
    while (64 * (bi + 1) - ((bi + 1) * bi) / 2 <= t) ++bi;
    while (64 * bi - (bi * (bi - 1)) / 2 > t) --bi;
    int bj = bi + (t - (64 * bi - (bi * (bi - 1)) / 2));
    const bool diag = (bi == bj);
    const int i0 = bi * 128;
    const int j0 = bj * 128;

    const int tid  = threadIdx.x;
    const int wave = tid >> 6;
    const int lane = tid & 63;
    const int quad = lane >> 4;
    const int lrow = lane & 15;
    const int i_w  = (wave >> 1) * 64;
    const int j_w  = (wave & 1) * 64;

    if (tid < 128)       labI[tid]       = labels[i0 + tid];
    else                 labJ[tid - 128] = labels[j0 + tid - 128];

    unsigned char* As = smem;
    float2* rowBuf = (float2*)smem;               // [2][128][9]  = 18432 B
    float2* colBuf = (float2*)(smem + 18432);     // [2][128][5]  = 10240 B
    const int vR = wave & 1;
    const int vC = wave >> 1;

    f32x4 acc[4][4];
    #pragma unroll
    for (int a = 0; a < 4; ++a)
        #pragma unroll
        for (int b = 0; b < 4; ++b)
            acc[a][b] = (f32x4){0.f, 0.f, 0.f, 0.f};

    const v4i* bptr[4];
    #pragma unroll
    for (int tj = 0; tj < 4; ++tj)
        bptr[tj] = (const v4i*)(E +
            (size_t)(j0 + j_w + tj * 16 + lrow) * DIM + quad * 32);

    v8i bf[2][4];
    #pragma unroll
    for (int tj = 0; tj < 4; ++tj) {      // prefetch B for k=0
        ((v4i*)&bf[0][tj])[0] = bptr[tj][0];
        ((v4i*)&bf[0][tj])[1] = bptr[tj][1];
    }

    // Two BK=256 A-chunks. Stage: wave rows [w*32,w*32+32), 8 instrs x 4 rows;
    // lane l: row base+(l>>4), LDS chunk p=l&15 holds global chunk p^(row&7).
    #pragma unroll
    for (int c = 0; c < 2; ++c) {
        if (c) __syncthreads();           // chunk0 ds_reads done
        #pragma unroll
        for (int h = 0; h < 8; ++h) {
            int base = wave * 32 + h * 4;
            int rowg = base + (lane >> 4);
            int g    = (lane & 15) ^ (rowg & 7);
            async_copy16(E + (size_t)(i0 + rowg) * DIM + c * 256 + g * 16,
                         As + (size_t)base * 256);
        }
        __syncthreads();                  // vmcnt drain: chunk ready

        #pragma unroll
        for (int k2 = 0; k2 < 2; ++k2) {
            const int k   = c * 2 + k2;
            const int cur = k & 1, nxt = cur ^ 1;
            v8i af[4];
            #pragma unroll
            for (int ti = 0; ti < 4; ++ti) {
                int r  = i_w + ti * 16 + lrow;
                const v4i* rp = (const v4i*)(As + (size_t)r * 256);
                int sw = r & 7;
                ((v4i*)&af[ti])[0] = rp[(k2 * 8 + quad * 2) ^ sw];
                ((v4i*)&af[ti])[1] = rp[(k2 * 8 + quad * 2 + 1) ^ sw];
            }
            if (k < 3) {                  // prefetch next k's B
                #pragma unroll
                for (int tj = 0; tj < 4; ++tj) {
                    ((v4i*)&bf[nxt][tj])[0] = bptr[tj][(k + 1) * 8];
                    ((v4i*)&bf[nxt][tj])[1] = bptr[tj][(k + 1) * 8 + 1];
                }
            }
            #pragma unroll
            for (int ti = 0; ti < 4; ++ti)
                #pragma unroll
                for (int tj = 0; tj < 4; ++tj)
                    acc[ti][tj] =
                        __builtin_amdgcn_mfma_scale_f32_16x16x128_f8f6f4(
                            af[ti], bf[cur][tj], acc[ti][tj],
                            0, 0,                 // fp8 e4m3 / e4m3
                            0, 0x7F7F7F7F,        // A scale = 1.0
                            0, 0x7F7F7F7F);       // B scale = 1.0
        }
    }
    __syncthreads();      // As dead -> reduction buffers writable

    // Compact epilogue (R12-proven). C/D: col = lane&15, row = quad*4 + reg.
    // acc = 16*S. Pre-reduce the 16 lrow partials to 8 via shfl_xor(8).
    float psC[4] = {0.f, 0.f, 0.f, 0.f};
    float nsC[4] = {0.f, 0.f, 0.f, 0.f};
    #pragma unroll
    for (int ti = 0; ti < 4; ++ti) {
        #pragma unroll
        for (int reg = 0; reg < 4; ++reg) {
            int irow = i_w + ti * 16 + quad * 4 + reg;
            int li   = labI[irow];
            int gi   = i0 + irow;
            float ps = 0.f, ns = 0.f;
            #pragma unroll
            for (int tj = 0; tj < 4; ++tj) {
                int jcol = j_w + tj * 16 + lrow;
                int lj   = labJ[jcol];
                int gj   = j0 + jcol;
                float w  = __expf(fmaf(acc[ti][tj][reg], 0.0625f, -1.0f));
                bool same = (li == lj);
                float wp = (same && (gi != gj)) ? w : 0.f;
                float wn = same ? 0.f : w;
                ps += wp;  ns += wn;
                psC[tj] += wp;  nsC[tj] += wn;
            }
            ps += __shfl_xor(ps, 8, 64);
            ns += __shfl_xor(ns, 8, 64);
            if ((lrow & 8) == 0)
                rowBuf[(size_t)(vR * 128 + irow) * 9 + lrow] = (float2){ps, ns};
        }
    }
    #pragma unroll
    for (int tj = 0; tj < 4; ++tj) {
        int jcol = j_w + tj * 16 + lrow;
        colBuf[(size_t)(vC * 128 + jcol) * 5 + quad] = (float2){psC[tj], nsC[tj]};
    }
    __syncthreads();

    if (tid < 128) {
        const float2* a = rowBuf + (size_t)tid * 9;
        const float2* b = rowBuf + (size_t)(128 + tid) * 9;
        float sp = 0.f, sn = 0.f;
        #pragma unroll
        for (int u2 = 0; u2 < 8; ++u2) {
            sp += a[u2].x + b[u2].x;
            sn += a[u2].y + b[u2].y;
        }
        P[(size_t)bj * BN + i0 + tid] = sp;
        N[(size_t)bj * BN + i0 + tid] = sn;
    } else if (!diag) {
        int c2 = tid - 128;
        const float2* a = colBuf + (size_t)c2 * 5;
        const float2* b = colBuf + (size_t)(128 + c2) * 5;
        float sp = 0.f, sn = 0.f;
        #pragma unroll
        for (int u2 = 0; u2 < 4; ++u2) {
            sp += a[u2].x + b[u2].x;
            sn += a[u2].y + b[u2].y;
        }
        P[(size_t)bi * BN + j0 + c2] = sp;
        N[(size_t)bi * BN + j0 + c2] = sn;
    }
}

// Fused tail: 32 blocks x 256. Per-block LDS histogram, per-row partial
// reduce + loss, one atomicAdd of the pre-scaled block sum into out[0].
__global__ __launch_bounds__(256) void reduce_finalize_kernel(
        const int* __restrict__ labels, const float* __restrict__ P,
        const float* __restrict__ N, float* __restrict__ out) {
    __shared__ int cnt[128];
    __shared__ float wsum[4];
    int tid = threadIdx.x;
    if (tid < 128) cnt[tid] = 0;
    __syncthreads();
    for (int i = tid; i < BN; i += 256) atomicAdd(&cnt[labels[i]], 1);
    __syncthreads();

    int i = blockIdx.x * 256 + tid;
    float p = 0.f, n = 0.f;
    #pragma unroll 8
    for (int c = 0; c < NB; ++c) {
        p += P[(size_t)c * BN + i];
        n += N[(size_t)c * BN + i];
    }
    int   cl = cnt[labels[i]];
    float pm = p / fmaxf((float)(cl - 1), 1.0f);
    float nm = n / fmaxf((float)(BN - cl), 1.0f);
    float v  = ((cl - 1 > 0) && (BN - cl > 0))
                   ? -logf(pm / (pm + nm + EPSF)) : 0.0f;
    v *= (1.0f / (float)BN);
    #pragma unroll
    for (int m = 1; m < 64; m <<= 1) v += __shfl_xor(v, m, 64);
    if ((tid & 63) == 0) wsum[tid >> 6] = v;
    __syncthreads();
    if (tid == 0)
        atomicAdd(out, wsum[0] + wsum[1] + wsum[2] + wsum[3]);
}

extern "C" void kernel_launch(void* const* d_in, const int* in_sizes, int n_in,
                              void* d_out, int out_size, void* d_ws, size_t ws_size,
                              hipStream_t stream) {
    const float* emb   = (const float*)d_in[0];
    const int* labels  = (const int*)d_in[1];
    float* out         = (float*)d_out;

    // ws layout: E (8 MB reserved; fp8 uses 4) | P (2 MB) | N (2 MB)
    unsigned char* E   = (unsigned char*)d_ws;
    float* P           = (float*)((char*)d_ws + (size_t)BN * DIM * 2);
    float* N           = P + (size_t)NB * BN;

    normalize_kernel<<<BN / 4, 256, 0, stream>>>(emb, E, out);
    gemm_epi_kernel<<<NTILES, 256, 0, stream>>>(E, labels, P, N);
    reduce_finalize_kernel<<<32, 256, 0, stream>>>(labels, P, N, out);
}